// Round 5
// baseline (433.431 us; speedup 1.0000x reference)
//
#include <hip/hip_runtime.h>
#include <math.h>

#define BATCH 32768
#define SEQLEN 200
#define PSTEPS 50
#define HID 32
#define LDS_PAD 36   // float row stride 36 -> mild bank aliasing only (m136)

typedef __attribute__((ext_vector_type(2))) _Float16 half2v;
typedef __attribute__((ext_vector_type(8))) _Float16 half8v;
typedef __attribute__((ext_vector_type(2))) __fp16   fp16x2;   // cvt_pkrtz return type
typedef __attribute__((ext_vector_type(4))) float floatx4;

#define EXP2 __builtin_amdgcn_exp2f      // v_exp_f32: 2^x
#define RCPF __builtin_amdgcn_rcpf       // v_rcp_f32
#define PKRTZ __builtin_amdgcn_cvt_pkrtz // v_cvt_pkrtz_f16_f32

#define L1C 1.4426950408889634f          // log2(e)
#define L2C 2.8853900817779268f          // 2*log2(e)

union H8 { unsigned int u[4]; half8v h; half2v h2[4]; };
union HU { fp16x2 h; unsigned int u; };

__device__ __forceinline__ unsigned int pk(float a, float b) {
    HU t; t.h = PKRTZ(a, b); return t.u;
}

// lgkm-only fence + barrier: keeps the x prefetch (vmcnt) in flight across
// the step boundary, unlike __syncthreads() which drains vmcnt(0).
__device__ __forceinline__ void lds_barrier() {
    asm volatile("s_waitcnt lgkmcnt(0)" ::: "memory");
    __builtin_amdgcn_s_barrier();
    asm volatile("" ::: "memory");
}

// One GROUP = 16 batch elements = one 128-thread block = 2 waves.
// Gate matrix per step: [16 batch x 128 gates]; gates rows: i=0-31 f=32-63
// g=64-95 o=96-127. Wave half h takes units u = half*16..half*16+15, i.e.
// 16-gate tiles {half, 2+half, 4+half, 6+half} -> 8 MFMAs + 4 cells/lane.
// h state ping-pongs between 2 LDS buffers; 1 raw s_barrier per step.
//   per gate tile: acc = mfma(ah, Bh, mfma(a2, B2, 0))
//   a2 (quad0): [x_f16(4) | 1 | 1 | 0 | 0]; B2 rows0-3 = W_ih, 4/5 = bias hi/lo
// C layout: row(batch)=quad*4+reg, col(gate)=lane&15; A: m=lane&15, k=quad*8+j.
__global__ __launch_bounds__(128, 4)
void lstm_mfma_kernel(const float* __restrict__ hist, const float* __restrict__ W_ih,
                      const float* __restrict__ W_hh, const float* __restrict__ b_ih,
                      const float* __restrict__ b_hh, const float* __restrict__ W_pred,
                      const float* __restrict__ b_pred, float* __restrict__ out)
{
    const int lane = threadIdx.x & 63;
    const int half = threadIdx.x >> 6;        // 0 or 1: which 16 hidden units
    const int m    = lane & 15;
    const int quad = lane >> 4;
    const int elem0 = blockIdx.x * 16;

    __shared__ __align__(16) float hbuf[2][16][LDS_PAD];   // ping-pong h state

    // ---- resident weight fragments (f16; this wave's 4 gate tiles) ----
    half8v Bh[4], B2[4];
    #pragma unroll
    for (int g = 0; g < 4; ++g) {
        const int gc = g * 32 + half * 16 + m;     // gate row for unit half*16+m
        H8 bh;
        #pragma unroll
        for (int jj = 0; jj < 4; ++jj) {
            bh.h2[jj] = (half2v){ (_Float16)W_hh[gc * HID + quad * 8 + 2 * jj],
                                  (_Float16)W_hh[gc * HID + quad * 8 + 2 * jj + 1] };
        }
        Bh[g] = bh.h;
        H8 b2; b2.u[0] = b2.u[1] = b2.u[2] = b2.u[3] = 0u;
        if (quad == 0) {
            b2.h2[0] = (half2v){ (_Float16)W_ih[gc * 4 + 0], (_Float16)W_ih[gc * 4 + 1] };
            b2.h2[1] = (half2v){ (_Float16)W_ih[gc * 4 + 2], (_Float16)W_ih[gc * 4 + 3] };
            float bsum = b_ih[gc] + b_hh[gc];
            _Float16 bhi = (_Float16)bsum;
            _Float16 blo = (_Float16)(bsum - (float)bhi);   // bias exact to ~2^-24
            b2.h2[2] = (half2v){ bhi, blo };                // K rows 4,5 (A = 1,1)
        }
        B2[g] = b2.h;
    }
    const unsigned int one2 = 0x3C003C00u;     // (1.0h, 1.0h)

    // ---- init h=0 in buf0 (each wave its half), c=0 in regs ----
    float cst[4];
    #pragma unroll
    for (int r = 0; r < 4; ++r) { cst[r] = 0.f; hbuf[0][quad * 4 + r][half * 16 + m] = 0.f; }
    lds_barrier();

    // ---- encode: 200 steps ----
    const float4* xp = (const float4*)(hist + (size_t)(elem0 + m) * (SEQLEN * 4));
    float4 xv = xp[0];
    #pragma unroll 1
    for (int t = 0; t < SEQLEN; ++t) {
        const int rd = t & 1;
        float4 h0 = *(const float4*)&hbuf[rd][m][quad * 8];
        float4 h1 = *(const float4*)&hbuf[rd][m][quad * 8 + 4];
        H8 ahu;
        ahu.u[0] = pk(h0.x, h0.y); ahu.u[1] = pk(h0.z, h0.w);
        ahu.u[2] = pk(h1.x, h1.y); ahu.u[3] = pk(h1.z, h1.w);
        const half8v ah = ahu.h;

        const unsigned int tx0 = pk(xv.x, xv.y), tx1 = pk(xv.z, xv.w);
        H8 a2u;
        a2u.u[0] = (quad == 0) ? tx0 : 0u;
        a2u.u[1] = (quad == 0) ? tx1 : 0u;
        a2u.u[2] = (quad == 0) ? one2 : 0u;
        a2u.u[3] = 0u;
        const half8v a2 = a2u.h;

        const int tn = (t + 1 < SEQLEN) ? t + 1 : SEQLEN - 1;
        float4 xn = xp[tn];                    // prefetch stays in flight (no vmcnt drain)

        floatx4 acc[4];                         // gates i,f,g,o for units half*16+m
        #pragma unroll
        for (int g = 0; g < 4; ++g) {
            floatx4 a = __builtin_amdgcn_mfma_f32_16x16x32_f16(a2, B2[g], (floatx4){0.f,0.f,0.f,0.f}, 0, 0, 0);
            acc[g] = __builtin_amdgcn_mfma_f32_16x16x32_f16(ah, Bh[g], a, 0, 0, 0);
        }
        #pragma unroll
        for (int r = 0; r < 4; ++r) {
            const float gi = acc[0][r], gf = acc[1][r], gg = acc[2][r], go = acc[3][r];
            const float ei = EXP2(gi * -L1C);
            const float ef = EXP2(gf * -L1C);
            const float eo = EXP2(go * -L1C);
            const float eg = EXP2(gg * L2C);
            // cn = c/(1+ef) + (eg-1)/((1+ei)(1+eg)), single shared rcp
            const float pf = 1.0f + ef;
            const float t1 = (1.0f + ei) * (1.0f + eg);
            const float num = fmaf(cst[r], t1, (eg - 1.0f) * pf);
            float cn = num * RCPF(t1 * pf);
            cn = fminf(fmaxf(cn, -30.0f), 30.0f);   // keep exp(2cn) finite
            const float ec = EXP2(cn * L2C);
            const float hn = (ec - 1.0f) * RCPF((1.0f + eo) * (1.0f + ec));
            cst[r] = cn;
            hbuf[rd ^ 1][quad * 4 + r][half * 16 + m] = hn;
        }
        lds_barrier();
        xv = xn;
    }

    // ---- decode: 50 steps (c reset to 0 -> f-gate dead) ----
    float wp[4][8];
    #pragma unroll
    for (int d = 0; d < 4; ++d)
        #pragma unroll
        for (int j = 0; j < 8; ++j) wp[d][j] = W_pred[d * HID + quad * 8 + j];
    float bp[4] = { b_pred[0], b_pred[1], b_pred[2], b_pred[3] };

    float* op = out + (size_t)(elem0 + m) * (PSTEPS * 4);
    #pragma unroll 1
    for (int p = 0; p < PSTEPS; ++p) {
        const int rd = p & 1;                  // encode ended with h in buf0
        float4 h0 = *(const float4*)&hbuf[rd][m][quad * 8];
        float4 h1 = *(const float4*)&hbuf[rd][m][quad * 8 + 4];
        const float hv[8] = { h0.x, h0.y, h0.z, h0.w, h1.x, h1.y, h1.z, h1.w };

        float pd[4];
        #pragma unroll
        for (int d = 0; d < 4; ++d) {
            float s = 0.f;
            #pragma unroll
            for (int j = 0; j < 8; ++j) s = fmaf(hv[j], wp[d][j], s);
            s += __shfl_xor(s, 16);
            s += __shfl_xor(s, 32);
            pd[d] = s + bp[d];
        }
        if (half == 0 && quad == 0) *(float4*)(op + p * 4) = make_float4(pd[0], pd[1], pd[2], pd[3]);

        if (p + 1 < PSTEPS) {
            H8 ahu;
            ahu.u[0] = pk(hv[0], hv[1]); ahu.u[1] = pk(hv[2], hv[3]);
            ahu.u[2] = pk(hv[4], hv[5]); ahu.u[3] = pk(hv[6], hv[7]);
            const half8v ah = ahu.h;
            const unsigned int tx0 = pk(pd[0], pd[1]), tx1 = pk(pd[2], pd[3]);
            H8 a2u;
            a2u.u[0] = (quad == 0) ? tx0 : 0u;
            a2u.u[1] = (quad == 0) ? tx1 : 0u;
            a2u.u[2] = (quad == 0) ? one2 : 0u;
            a2u.u[3] = 0u;
            const half8v a2 = a2u.h;

            floatx4 acc[3];                    // gates i,g,o (f dead: c==0)
            #pragma unroll
            for (int k = 0; k < 3; ++k) {
                const int g = (k == 0) ? 0 : k + 1;   // Bh idx 0,2,3 = i,g,o
                floatx4 a = __builtin_amdgcn_mfma_f32_16x16x32_f16(a2, B2[g], (floatx4){0.f,0.f,0.f,0.f}, 0, 0, 0);
                acc[k] = __builtin_amdgcn_mfma_f32_16x16x32_f16(ah, Bh[g], a, 0, 0, 0);
            }
            #pragma unroll
            for (int r = 0; r < 4; ++r) {
                const float gi = acc[0][r], gg = acc[1][r], go = acc[2][r];
                const float ei = EXP2(gi * -L1C);
                const float eo = EXP2(go * -L1C);
                const float eg = EXP2(gg * L2C);
                const float cn = (eg - 1.0f) * RCPF((1.0f + ei) * (1.0f + eg)); // |cn|<1
                const float ec = EXP2(cn * L2C);
                const float hn = (ec - 1.0f) * RCPF((1.0f + eo) * (1.0f + ec));
                hbuf[rd ^ 1][quad * 4 + r][half * 16 + m] = hn;
            }
            lds_barrier();
        }
    }
}

extern "C" void kernel_launch(void* const* d_in, const int* in_sizes, int n_in,
                              void* d_out, int out_size, void* d_ws, size_t ws_size,
                              hipStream_t stream) {
    const float* hist   = (const float*)d_in[0];
    const float* W_ih   = (const float*)d_in[1];
    const float* W_hh   = (const float*)d_in[2];
    const float* b_ih   = (const float*)d_in[3];
    const float* b_hh   = (const float*)d_in[4];
    const float* W_pred = (const float*)d_in[5];
    const float* b_pred = (const float*)d_in[6];
    float* out = (float*)d_out;

    const int blocks = BATCH / 16;   // 2048 blocks x 128 thr = 4096 waves = 4/SIMD
    lstm_mfma_kernel<<<blocks, 128, 0, stream>>>(hist, W_ih, W_hh, b_ih, b_hh,
                                                 W_pred, b_pred, out);
}